// Round 7
// baseline (1080.353 us; speedup 1.0000x reference)
//
#include <hip/hip_runtime.h>

// Problem constants
#define B_    8
#define CIN_  16
#define COUT_ 16
#define KS_   13
#define AS_   12
#define P_    4096
#define R_    12
#define M_    192          // COUT_ * R_
#define KTOT  2496         // CIN_ * KS_ * AS_   (reduction dim)
#define BN    128          // p-tile per workgroup (256 WGs, 1/CU)
#define KT    96           // K-tile (8 (c,k) pairs x 12 a)
#define NSTEP 26           // KTOT / KT
#define LDP   104          // LDS pitch (96 + 8 pad)

typedef float  f32x4  __attribute__((ext_vector_type(4)));
typedef __bf16 bf16x4 __attribute__((ext_vector_type(4)));
typedef __bf16 bf16x8 __attribute__((ext_vector_type(8)));

// ---------------------------------------------------------------------------
// Kernel 1: expand W (16x16x36) -> Wmat[m=(d*12+r)][kappa=(c*13+k)*12+a] bf16
// ---------------------------------------------------------------------------
__global__ void build_wmat(const float* __restrict__ W,
                           const int* __restrict__ idx_map,
                           const int* __restrict__ tivr,   // [12][13]
                           const int* __restrict__ tir,    // [12][12]
                           __bf16* __restrict__ Wmat) {
  int m = blockIdx.x;            // 0..191
  int d = m / R_;
  int r = m - d * R_;
  for (int kap = threadIdx.x; kap < KTOT; kap += blockDim.x) {
    int c = kap / (KS_ * AS_);
    int t = kap - c * (KS_ * AS_);
    int k = t / AS_;
    int a = t - k * AS_;
    int s = idx_map[tivr[r * KS_ + k] * AS_ + tir[r * AS_ + a]];
    Wmat[m * KTOT + kap] = (__bf16)W[(d * CIN_ + c) * 36 + s];
  }
}

// ---------------------------------------------------------------------------
// Kernel 2 (REAL, identical to R4 = best 78.1 us): out = Wmat @ X
// ---------------------------------------------------------------------------
__global__ __launch_bounds__(512, 2)
void s2conv(const float* __restrict__ x,
            const __bf16* __restrict__ Wmat,
            float* __restrict__ out) {
  __shared__ __bf16 Ws[2][M_][LDP];
  __shared__ __bf16 Xs[2][BN][LDP];

  const int tid  = threadIdx.x;
  const int lane = tid & 63;
  const int wave = tid >> 6;
  const int wm   = wave >> 2;
  const int wn   = wave & 3;
  const int l15  = lane & 15;
  const int l4   = lane >> 4;

  const int wg = blockIdx.x;
  const int b  = wg >> 5;
  const int p0 = (wg & 31) << 7;

  int wrow[4], wchk[4];
#pragma unroll
  for (int j = 0; j < 4; ++j) {
    int i = tid + j * 512;
    wrow[j] = i / 12;
    wchk[j] = i - wrow[j] * 12;
  }
  const int ti   = 2048 + (tid >> 1);
  const int trow = ti / 12;
  const int tchk = ti - trow * 12;
  const int thalf = (tid & 1) * 8;

  f32x4 acc[6][2];
#pragma unroll
  for (int i = 0; i < 6; ++i)
#pragma unroll
    for (int j = 0; j < 2; ++j)
      acc[i][j] = f32x4{0.f, 0.f, 0.f, 0.f};

  auto load_x = [&](int kt, f32x4 (&st)[6]) {
    int ck = kt * 8 + wave;
    const f32x4* bp =
        (const f32x4*)(x + (size_t)(b * 208 + ck) * 49152 + (size_t)p0 * 12);
#pragma unroll
    for (int it = 0; it < 6; ++it) st[it] = bp[it * 64 + lane];
  };

  auto load_w = [&](int kt, bf16x8 (&w4)[4], bf16x4& wt) {
    const char* wb = (const char*)Wmat + (size_t)kt * (KT * 2);
#pragma unroll
    for (int j = 0; j < 4; ++j)
      w4[j] = *(const bf16x8*)(wb + (size_t)wrow[j] * (KTOT * 2) + wchk[j] * 16);
    wt = *(const bf16x4*)(wb + (size_t)trow * (KTOT * 2) + tchk * 16 + thalf);
  };

  auto write_tiles = [&](int buf, f32x4 (&st)[6], bf16x8 (&w4)[4], bf16x4& wt) {
    char* wsb = (char*)&Ws[buf][0][0];
    char* xsb = (char*)&Xs[buf][0][0];
#pragma unroll
    for (int j = 0; j < 4; ++j)
      *(bf16x8*)(wsb + wrow[j] * (LDP * 2) + wchk[j] * 16) = w4[j];
    *(bf16x4*)(wsb + trow * (LDP * 2) + tchk * 16 + thalf) = wt;
#pragma unroll
    for (int it = 0; it < 6; ++it) {
      int f4i = it * 64 + lane;
      int pl  = f4i / 3;
      int a   = (f4i - pl * 3) * 4;
      bf16x4 v = __builtin_convertvector(st[it], bf16x4);
      *(bf16x4*)(xsb + pl * (LDP * 2) + (wave * 12 + a) * 2) = v;
    }
  };

  auto mfma_step = [&](int buf) {
    const __bf16* wsb = &Ws[buf][0][0];
    const __bf16* xsb = &Xs[buf][0][0];
#pragma unroll
    for (int ks = 0; ks < 3; ++ks) {
      const int col = ks * 32 + l4 * 8;
      bf16x8 af[6], bfr[2];
#pragma unroll
      for (int mt = 0; mt < 6; ++mt)
        af[mt] = *(const bf16x8*)(wsb + (wm * 96 + mt * 16 + l15) * LDP + col);
#pragma unroll
      for (int nt = 0; nt < 2; ++nt)
        bfr[nt] = *(const bf16x8*)(xsb + (wn * 32 + nt * 16 + l15) * LDP + col);
#pragma unroll
      for (int mt = 0; mt < 6; ++mt)
#pragma unroll
        for (int nt = 0; nt < 2; ++nt)
          acc[mt][nt] = __builtin_amdgcn_mfma_f32_16x16x32_bf16(
              af[mt], bfr[nt], acc[mt][nt], 0, 0, 0);
    }
  };

  auto barrier = [&]() {
    asm volatile("s_waitcnt lgkmcnt(0)" ::: "memory");
    __builtin_amdgcn_s_barrier();
  };

  f32x4  stA[6], stB[6];
  bf16x8 wA4[4], wB4[4];
  bf16x4 wAt, wBt;
  load_x(0, stA); load_w(0, wA4, wAt);
  load_x(1, stB); load_w(1, wB4, wBt);
  write_tiles(0, stA, wA4, wAt);
  barrier();

  for (int kt = 0; kt < NSTEP - 2; kt += 2) {
    load_x(kt + 2, stA); load_w(kt + 2, wA4, wAt);
    __builtin_amdgcn_sched_barrier(0);
    write_tiles(1, stB, wB4, wBt);
    mfma_step(0);
    barrier();

    load_x(kt + 3, stB); load_w(kt + 3, wB4, wBt);
    __builtin_amdgcn_sched_barrier(0);
    write_tiles(0, stA, wA4, wAt);
    mfma_step(1);
    barrier();
  }

  write_tiles(1, stB, wB4, wBt);
  mfma_step(0);
  barrier();
  mfma_step(1);

#pragma unroll
  for (int mt = 0; mt < 6; ++mt) {
    int mrow0 = wm * 96 + mt * 16 + l4 * 4;
    int d  = mrow0 / 12;
    int r0 = mrow0 - d * 12;
#pragma unroll
    for (int nt = 0; nt < 2; ++nt) {
      int p = p0 + wn * 32 + nt * 16 + l15;
      float* dst = out + (size_t)((b * 16 + d) * 4096 + p) * 12 + r0;
      *(f32x4*)dst = acc[mt][nt];
    }
  }
}

// ---------------------------------------------------------------------------
// ABLATION kernels (no output; REP repeats so each lands in rocprof top-5).
// G: real global loads    L: real LDS write/read + lgkm barrier    M: real MFMA
// Keep-alive asm prevents DCE; never-taken guard keeps LDS allocated so
// occupancy matches the real kernel (1 WG/CU).
// ---------------------------------------------------------------------------
template <int G, int L, int M, int REP>
__global__ __launch_bounds__(512, 2)
void s2ab(const float* __restrict__ x, const __bf16* __restrict__ Wmat) {
  __shared__ __bf16 Ws[2][M_][LDP];
  __shared__ __bf16 Xs[2][BN][LDP];

  const int tid  = threadIdx.x;
  const int lane = tid & 63;
  const int wave = tid >> 6;
  const int wm   = wave >> 2;
  const int wn   = wave & 3;
  const int l15  = lane & 15;
  const int l4   = lane >> 4;
  const int wg = blockIdx.x;
  const int b  = wg >> 5;
  const int p0 = (wg & 31) << 7;

  // keep LDS allocated even when L==0 (runtime-opaque never-true guard)
  if ((int)blockIdx.x == 0x7fffffff) {
    Ws[0][0][0] = (__bf16)1.0f;
    Xs[0][0][0] = (__bf16)1.0f;
    asm volatile("" ::: "memory");
  }

  int wrow[4], wchk[4];
#pragma unroll
  for (int j = 0; j < 4; ++j) {
    int i = tid + j * 512;
    wrow[j] = i / 12;
    wchk[j] = i - wrow[j] * 12;
  }
  const int ti   = 2048 + (tid >> 1);
  const int trow = ti / 12;
  const int tchk = ti - trow * 12;
  const int thalf = (tid & 1) * 8;

  f32x4 acc[6][2];
#pragma unroll
  for (int i = 0; i < 6; ++i)
#pragma unroll
    for (int j = 0; j < 2; ++j)
      acc[i][j] = f32x4{0.f, 0.f, 0.f, 0.f};

  auto load_x = [&](int kt, f32x4 (&st)[6]) {
    if constexpr (G) {
      int ck = kt * 8 + wave;
      const f32x4* bp =
          (const f32x4*)(x + (size_t)(b * 208 + ck) * 49152 + (size_t)p0 * 12);
#pragma unroll
      for (int it = 0; it < 6; ++it) st[it] = bp[it * 64 + lane];
    } else {
#pragma unroll
      for (int it = 0; it < 6; ++it)
        st[it] = f32x4{(float)(lane + it), 0.5f, 0.25f, 0.125f};
    }
  };

  auto load_w = [&](int kt, bf16x8 (&w4)[4], bf16x4& wt) {
    if constexpr (G) {
      const char* wb = (const char*)Wmat + (size_t)kt * (KT * 2);
#pragma unroll
      for (int j = 0; j < 4; ++j)
        w4[j] = *(const bf16x8*)(wb + (size_t)wrow[j] * (KTOT * 2) + wchk[j] * 16);
      wt = *(const bf16x4*)(wb + (size_t)trow * (KTOT * 2) + tchk * 16 + thalf);
    } else {
#pragma unroll
      for (int j = 0; j < 4; ++j)
#pragma unroll
        for (int e = 0; e < 8; ++e) w4[j][e] = (__bf16)(float)(lane + e + j);
#pragma unroll
      for (int e = 0; e < 4; ++e) wt[e] = (__bf16)(float)(lane + e);
    }
  };

  auto write_tiles = [&](int buf, f32x4 (&st)[6], bf16x8 (&w4)[4], bf16x4& wt) {
    if constexpr (L) {
      char* wsb = (char*)&Ws[buf][0][0];
      char* xsb = (char*)&Xs[buf][0][0];
#pragma unroll
      for (int j = 0; j < 4; ++j)
        *(bf16x8*)(wsb + wrow[j] * (LDP * 2) + wchk[j] * 16) = w4[j];
      *(bf16x4*)(wsb + trow * (LDP * 2) + tchk * 16 + thalf) = wt;
#pragma unroll
      for (int it = 0; it < 6; ++it) {
        int f4i = it * 64 + lane;
        int pl  = f4i / 3;
        int a   = (f4i - pl * 3) * 4;
        bf16x4 v = __builtin_convertvector(st[it], bf16x4);
        *(bf16x4*)(xsb + pl * (LDP * 2) + (wave * 12 + a) * 2) = v;
      }
    } else {
      // consume staged regs at the same point a real write would (forces the
      // same counted vmcnt wait), but no LDS traffic
#pragma unroll
      for (int it = 0; it < 6; ++it) asm volatile("" :: "v"(st[it]));
#pragma unroll
      for (int j = 0; j < 4; ++j) asm volatile("" :: "v"(w4[j]));
      asm volatile("" :: "v"(wt));
    }
  };

  auto mfma_step = [&](int buf) {
    if constexpr (L) {
      const __bf16* wsb = &Ws[buf][0][0];
      const __bf16* xsb = &Xs[buf][0][0];
#pragma unroll
      for (int ks = 0; ks < 3; ++ks) {
        const int col = ks * 32 + l4 * 8;
        bf16x8 af[6], bfr[2];
#pragma unroll
        for (int mt = 0; mt < 6; ++mt)
          af[mt] = *(const bf16x8*)(wsb + (wm * 96 + mt * 16 + l15) * LDP + col);
#pragma unroll
        for (int nt = 0; nt < 2; ++nt)
          bfr[nt] = *(const bf16x8*)(xsb + (wn * 32 + nt * 16 + l15) * LDP + col);
        if constexpr (M) {
#pragma unroll
          for (int mt = 0; mt < 6; ++mt)
#pragma unroll
            for (int nt = 0; nt < 2; ++nt)
              acc[mt][nt] = __builtin_amdgcn_mfma_f32_16x16x32_bf16(
                  af[mt], bfr[nt], acc[mt][nt], 0, 0, 0);
        } else {
#pragma unroll
          for (int mt = 0; mt < 6; ++mt) asm volatile("" :: "v"(af[mt]));
          asm volatile("" :: "v"(bfr[0]));
          asm volatile("" :: "v"(bfr[1]));
        }
      }
    }
  };

  auto barrier = [&]() {
    if constexpr (L) asm volatile("s_waitcnt lgkmcnt(0)" ::: "memory");
    __builtin_amdgcn_s_barrier();
  };

  for (int rep = 0; rep < REP; ++rep) {
    f32x4  stA[6], stB[6];
    bf16x8 wA4[4], wB4[4];
    bf16x4 wAt, wBt;
    load_x(0, stA); load_w(0, wA4, wAt);
    load_x(1, stB); load_w(1, wB4, wBt);
    write_tiles(0, stA, wA4, wAt);
    barrier();

    for (int kt = 0; kt < NSTEP - 2; kt += 2) {
      load_x(kt + 2, stA); load_w(kt + 2, wA4, wAt);
      __builtin_amdgcn_sched_barrier(0);
      write_tiles(1, stB, wB4, wBt);
      mfma_step(0);
      barrier();

      load_x(kt + 3, stB); load_w(kt + 3, wB4, wBt);
      __builtin_amdgcn_sched_barrier(0);
      write_tiles(0, stA, wA4, wAt);
      mfma_step(1);
      barrier();
    }

    write_tiles(1, stB, wB4, wBt);
    mfma_step(0);
    barrier();
    mfma_step(1);
    barrier();
  }

#pragma unroll
  for (int i = 0; i < 6; ++i)
    asm volatile("" :: "v"(acc[i][0]), "v"(acc[i][1]));
}

// ---------------------------------------------------------------------------
extern "C" void kernel_launch(void* const* d_in, const int* in_sizes, int n_in,
                              void* d_out, int out_size, void* d_ws, size_t ws_size,
                              hipStream_t stream) {
  const float* x       = (const float*)d_in[0];
  const float* W       = (const float*)d_in[1];
  const int*   idx_map = (const int*)d_in[2];
  const int*   tivr    = (const int*)d_in[3];
  const int*   tir     = (const int*)d_in[4];
  float*       out     = (float*)d_out;
  __bf16*      Wmat    = (__bf16*)d_ws;          // 192*2496 bf16 = 958 KB

  build_wmat<<<dim3(M_), dim3(256), 0, stream>>>(W, idx_map, tivr, tir, Wmat);
  s2conv<<<dim3(256), dim3(512), 0, stream>>>(x, Wmat, out);   // REAL (R4)

  // --- instrumentation dispatches (read-only; timings/counters via rocprof) --
  s2ab<1, 1, 1, 4><<<dim3(256), dim3(512), 0, stream>>>(x, Wmat);  // full
  s2ab<1, 1, 0, 6><<<dim3(256), dim3(512), 0, stream>>>(x, Wmat);  // stage
  s2ab<0, 1, 1, 8><<<dim3(256), dim3(512), 0, stream>>>(x, Wmat);  // compute
  s2ab<1, 0, 0, 6><<<dim3(256), dim3(512), 0, stream>>>(x, Wmat);  // hbm
}

// Round 8
// 78.110 us; speedup vs baseline: 13.8312x; 13.8312x over previous
//
#include <hip/hip_runtime.h>
#include <stdint.h>

// Problem constants
#define CIN_  16
#define KS_   13
#define AS_   12
#define R_    12
#define KT    96            // kappa per step
#define NSTEP 26

typedef float  f32x4  __attribute__((ext_vector_type(4)));
typedef __bf16 bf16x4 __attribute__((ext_vector_type(4)));
typedef __bf16 bf16x8 __attribute__((ext_vector_type(8)));

__device__ static inline void gll16(const void* g, void* l) {
  __builtin_amdgcn_global_load_lds(
      (const __attribute__((address_space(1))) uint32_t*)g,
      (__attribute__((address_space(3))) uint32_t*)l, 16, 0, 0);
}

// ---------------------------------------------------------------------------
// Kernel 1: expand W into MFMA-fragment-ordered WmatF.
// Frag fid = kt*36 + ks*12 + mt  (1 KB each: 64 lanes x 16B).
// Lane l, elem e:  A[row = mt*16 + (l&15)][kappa = kt*96 + ks*32 + (l>>4)*8 + e]
// with row=(d*12+r), kappa=(c*13+k)*12+a,
//   Wfull[d,c,r,k,a] = W[d,c, idx_map[ tivr[r,k]*12 + tir[r,a] ]].
// ---------------------------------------------------------------------------
__global__ void build_wmatf(const float* __restrict__ W,
                            const int* __restrict__ idx_map,
                            const int* __restrict__ tivr,   // [12][13]
                            const int* __restrict__ tir,    // [12][12]
                            __bf16* __restrict__ WmatF) {
  int gid  = blockIdx.x * blockDim.x + threadIdx.x;   // 0..59903 (= 936*64)
  int lane = gid & 63;
  int fid  = gid >> 6;              // 0..935
  int kt   = fid / 36;
  int rem  = fid - kt * 36;
  int ks   = rem / 12;
  int mt   = rem - ks * 12;

  int row = mt * 16 + (lane & 15);
  int d = row / R_;
  int r = row - d * R_;

  bf16x8 v;
#pragma unroll
  for (int e = 0; e < 8; ++e) {
    int kap = kt * KT + ks * 32 + (lane >> 4) * 8 + e;
    int c = kap / (KS_ * AS_);
    int t = kap - c * (KS_ * AS_);
    int k = t / AS_;
    int a = t - k * AS_;
    int s = idx_map[tivr[r * KS_ + k] * AS_ + tir[r * AS_ + a]];
    v[e] = (__bf16)W[(d * CIN_ + c) * 36 + s];
  }
  *(bf16x8*)(WmatF + (size_t)gid * 8) = v;
}

// ---------------------------------------------------------------------------
// Kernel 2: out(b,d,p,r) = Wmat(192 x 2496) @ X(2496 x [b,p])
// 256 WGs x 512 threads. 8 waves, each owns a PRIVATE 16-column p-slice and
// all 192 rows (12 MFMA tiles). B-fragments gathered DIRECTLY from global x
// (each lane: its column, 8-kappa runs as 2x dwordx4) -> X never in LDS,
// x read exactly once from HBM. A staged via global_load_lds from
// fragment-ordered WmatF (L2-hot), double-buffered, conflict-free b128 reads.
// Per step: one s_waitcnt vmcnt(6) + bare s_barrier. Never vmcnt(0).
// ---------------------------------------------------------------------------
__global__ __launch_bounds__(512, 2)
void s2conv(const float* __restrict__ x,
            const __bf16* __restrict__ WmatF,
            float* __restrict__ out) {
  __shared__ __bf16 As[2][36 * 512];   // 2 x 36 frags x 1 KB = 72 KB

  const int tid  = threadIdx.x;
  const int lane = tid & 63;
  const int wave = tid >> 6;        // 0..7 -> 16-col group
  const int l15  = lane & 15;
  const int l4   = lane >> 4;

  const int wg = blockIdx.x;        // 0..255
  const int b  = wg >> 5;           // 0..7
  const int p0 = (wg & 31) << 7;
  const int p  = p0 + wave * 16 + l15;   // this thread's private column

  // B-load byte offsets for the 6 (ks,half) slots: 4 consecutive floats at
  // kappa_local = ks*32 + l4*8 + h*4  ->  (ck, a); never crosses ck (a%4==0).
  int voff[3][2];
#pragma unroll
  for (int ks = 0; ks < 3; ++ks)
#pragma unroll
    for (int h = 0; h < 2; ++h) {
      int kl = ks * 32 + l4 * 8 + h * 4;
      int ck = kl / 12, a = kl - ck * 12;
      voff[ks][h] = (ck * 49152 + a + p * 12) * 4;
    }
  const char* xb = (const char*)(x + (size_t)b * 208 * 49152);

  f32x4 acc[12];
#pragma unroll
  for (int i = 0; i < 12; ++i) acc[i] = f32x4{0.f, 0.f, 0.f, 0.f};

  // gll frag assignment: every wave exactly 5 (frags 32..35 staged twice,
  // same bytes -> benign). Uniform count => counted vmcnt stays exact.
  const int fr0 = wave * 4;
  const int fr4 = 32 + (wave & 3);

  auto stageA = [&](int kt, int buf) {
    const char* gk = (const char*)WmatF + (size_t)kt * 36864;
    char* lb = (char*)&As[buf][0];
#pragma unroll
    for (int f = 0; f < 4; ++f) {
      int frag = fr0 + f;
      gll16(gk + frag * 1024 + lane * 16, lb + frag * 1024);
    }
    gll16(gk + fr4 * 1024 + lane * 16, lb + fr4 * 1024);
  };

  auto loadB = [&](int kt, f32x4 (&bs)[3][2]) {
    const char* xk = xb + (size_t)kt * (8 * 49152 * 4);
#pragma unroll
    for (int ks = 0; ks < 3; ++ks)
#pragma unroll
      for (int h = 0; h < 2; ++h)
        bs[ks][h] = *(const f32x4*)(xk + voff[ks][h]);
  };

  auto mfma_phase = [&](int buf, f32x4 (&bs)[3][2]) {
    const char* lb = (const char*)&As[buf][0];
#pragma unroll
    for (int ks = 0; ks < 3; ++ks) {
      bf16x4 lo = __builtin_convertvector(bs[ks][0], bf16x4);
      bf16x4 hi = __builtin_convertvector(bs[ks][1], bf16x4);
      bf16x8 bfr = __builtin_shufflevector(lo, hi, 0, 1, 2, 3, 4, 5, 6, 7);
#pragma unroll
      for (int mt = 0; mt < 12; ++mt) {
        bf16x8 af = *(const bf16x8*)(lb + (ks * 12 + mt) * 1024 + lane * 16);
        acc[mt] = __builtin_amdgcn_mfma_f32_16x16x32_bf16(af, bfr, acc[mt],
                                                          0, 0, 0);
      }
    }
  };

  f32x4 bsE[3][2], bsO[3][2];

  // ---- prologue: tile 0 ----------------------------------------------------
  stageA(0, 0);
  __builtin_amdgcn_sched_barrier(0);
  loadB(0, bsE);
  __builtin_amdgcn_sched_barrier(0);
  asm volatile("s_waitcnt vmcnt(6)" ::: "memory");   // A(0) landed; B(0) flies
  __builtin_amdgcn_s_barrier();

  // ---- main loop: steps 0..24 fully unconditional --------------------------
  // step j: issue A(j+1)+B(j+1); MFMA tile j; vmcnt(6) (drain only the glls,
  // B(j+1) stays in flight); barrier.
#pragma unroll 1
  for (int j = 0; j < 24; j += 2) {
    stageA(j + 1, 1);
    __builtin_amdgcn_sched_barrier(0);
    loadB(j + 1, bsO);
    __builtin_amdgcn_sched_barrier(0);
    mfma_phase(0, bsE);
    asm volatile("s_waitcnt vmcnt(6)" ::: "memory");
    __builtin_amdgcn_s_barrier();

    stageA(j + 2, 0);
    __builtin_amdgcn_sched_barrier(0);
    loadB(j + 2, bsE);
    __builtin_amdgcn_sched_barrier(0);
    mfma_phase(1, bsO);
    asm volatile("s_waitcnt vmcnt(6)" ::: "memory");
    __builtin_amdgcn_s_barrier();
  }
  // step 24
  stageA(25, 1);
  __builtin_amdgcn_sched_barrier(0);
  loadB(25, bsO);
  __builtin_amdgcn_sched_barrier(0);
  mfma_phase(0, bsE);
  asm volatile("s_waitcnt vmcnt(6)" ::: "memory");
  __builtin_amdgcn_s_barrier();
  // step 25 (tail: no new loads)
  mfma_phase(1, bsO);

  // ---- epilogue: C layout col=l15 (=p), row = mt*16 + l4*4 + reg ----------
#pragma unroll
  for (int mt = 0; mt < 12; ++mt) {
    int mrow0 = mt * 16 + l4 * 4;        // r0 in {0,4,8} -> same d
    int d  = mrow0 / 12;
    int r0 = mrow0 - d * 12;
    float* dst = out + (size_t)((b * 16 + d) * 4096 + p) * 12 + r0;
    *(f32x4*)dst = acc[mt];              // 16B aligned
  }
}

// ---------------------------------------------------------------------------
extern "C" void kernel_launch(void* const* d_in, const int* in_sizes, int n_in,
                              void* d_out, int out_size, void* d_ws, size_t ws_size,
                              hipStream_t stream) {
  const float* x       = (const float*)d_in[0];  // (8,16,13,4096,12) f32
  const float* W       = (const float*)d_in[1];  // (16,16,36) f32
  const int*   idx_map = (const int*)d_in[2];    // (156,)
  const int*   tivr    = (const int*)d_in[3];    // (12,13)
  const int*   tir     = (const int*)d_in[4];    // (12,12)
  float*       out     = (float*)d_out;          // (8,16,4096,12) f32
  __bf16*      WmatF   = (__bf16*)d_ws;          // 936 KB, fragment-ordered

  build_wmatf<<<dim3(117), dim3(512), 0, stream>>>(W, idx_map, tivr, tir, WmatF);
  s2conv<<<dim3(256), dim3(512), 0, stream>>>(x, WmatF, out);
}